// Round 1
// baseline (338.130 us; speedup 1.0000x reference)
//
#include <hip/hip_runtime.h>

#define LDM 33
#define LDH 36

// ---------------------------------------------------------------------------
// Kernel 1: scatter edges into per-block 32x32 u8 count matrices (packed in u32)
// ---------------------------------------------------------------------------
__global__ __launch_bounds__(256) void build_adj(
    const int* __restrict__ row, const int* __restrict__ col,
    unsigned int* __restrict__ adj, int E)
{
    const int gid = blockIdx.x * blockDim.x + threadIdx.x;
    const int stride = gridDim.x * blockDim.x;
    const int E4 = E >> 2;
    const int4* row4 = reinterpret_cast<const int4*>(row);
    const int4* col4 = reinterpret_cast<const int4*>(col);
    for (int i = gid; i < E4; i += stride) {
        int4 r = row4[i];
        int4 c = col4[i];
        int idx;
        idx = ((r.x >> 5) << 10) + ((r.x & 31) << 5) + (c.x & 31);
        atomicAdd(&adj[idx >> 2], 1u << ((idx & 3) << 3));
        idx = ((r.y >> 5) << 10) + ((r.y & 31) << 5) + (c.y & 31);
        atomicAdd(&adj[idx >> 2], 1u << ((idx & 3) << 3));
        idx = ((r.z >> 5) << 10) + ((r.z & 31) << 5) + (c.z & 31);
        atomicAdd(&adj[idx >> 2], 1u << ((idx & 3) << 3));
        idx = ((r.w >> 5) << 10) + ((r.w & 31) << 5) + (c.w & 31);
        atomicAdd(&adj[idx >> 2], 1u << ((idx & 3) << 3));
    }
    // tail (E not multiple of 4)
    const int tail = E & 3;
    if (gid < tail) {
        int e = (E4 << 2) + gid;
        int r = row[e], c = col[e];
        int idx = ((r >> 5) << 10) + ((r & 31) << 5) + (c & 31);
        atomicAdd(&adj[idx >> 2], 1u << ((idx & 3) << 3));
    }
}

// ---------------------------------------------------------------------------
// Kernel 2: one 64-lane wave per subgraph. Full 3-layer GCN + JK + MLP head.
// Lane (n = l&31, half = l>>5) owns node n, feature dims [16*half, 16*half+16).
// ---------------------------------------------------------------------------
__global__ __launch_bounds__(64) void igmc_kernel(
    const float4* __restrict__ feats4,
    const uchar4* __restrict__ adj4,
    const float* __restrict__ W1, const float* __restrict__ b1,
    const float* __restrict__ W2, const float* __restrict__ b2,
    const float* __restrict__ W3, const float* __restrict__ b3,
    const float* __restrict__ lin1W, const float* __restrict__ lin1b,
    const float* __restrict__ lin2W, const float* __restrict__ lin2b,
    float* __restrict__ out)
{
    __shared__ __align__(16) float M[32 * LDM];    // M[v][u], LD=33: conflict-free scalar
    __shared__ __align__(16) float Ha[32 * LDH];   // LD=36: 16B-aligned float4 rows
    __shared__ __align__(16) float Hb[32 * LDH];
    __shared__ __align__(16) float sW1[4 * 32];
    __shared__ __align__(16) float sW2[32 * 32];
    __shared__ __align__(16) float sW3[32 * 32];
    __shared__ float sb1[32], sb2[32], sb3[32];
    __shared__ float ns[32], nd[32];
    __shared__ __align__(16) float rep[2 * 96];    // [user(96) | item(96)] JK reps

    const int b = blockIdx.x;
    const int l = threadIdx.x;
    const int half = l >> 5;
    const int n = l & 31;
    const int d0 = half << 4;   // 0 or 16

    // ---- stage weights into LDS ----
    for (int i = l; i < 1024; i += 64) { sW2[i] = W2[i]; sW3[i] = W3[i]; }
    for (int i = l; i < 128; i += 64) sW1[i] = W1[i];
    if (l < 32) { sb1[l] = b1[l]; sb2[l] = b2[l]; sb3[l] = b3[l]; }

    // ---- load adjacency counts (u8) -> Ha[u][v] as float ----
    #pragma unroll
    for (int j = 0; j < 4; ++j) {
        int q = (l << 2) + j;                 // uchar4 index 0..255
        uchar4 cc = adj4[(size_t)b * 256 + q];
        int base = q << 2;                    // byte index 0..1023
        int u = base >> 5, v = base & 31;
        float* p = &Ha[u * LDH + v];
        p[0] = (float)cc.x; p[1] = (float)cc.y; p[2] = (float)cc.z; p[3] = (float)cc.w;
    }
    __syncthreads();

    // ---- degrees -> norms ----
    {
        float s = 0.f;
        if (half == 0) {
            #pragma unroll
            for (int v = 0; v < 32; ++v) s += Ha[n * LDH + v];
            ns[n] = rsqrtf(fmaxf(s, 1.f));    // out_deg (row sums)
        } else {
            #pragma unroll
            for (int u = 0; u < 32; ++u) s += Ha[u * LDH + n];
            nd[n] = rsqrtf(fmaxf(s, 1.f));    // in_deg (col sums)
        }
    }
    __syncthreads();

    // ---- M[v][u] = A[u][v] * ns[u] * nd[v]; also load feats x -> Hb cols 0..3 ----
    #pragma unroll
    for (int j = 0; j < 16; ++j) {
        int idx = (l << 4) + j;               // 0..1023
        int v = idx >> 5, u = idx & 31;
        M[v * LDM + u] = Ha[u * LDH + v] * ns[u] * nd[v];
    }
    if (half == 0) {
        float4 f = feats4[b * 32 + n];
        Hb[n * LDH + 0] = f.x; Hb[n * LDH + 1] = f.y;
        Hb[n * LDH + 2] = f.z; Hb[n * LDH + 3] = f.w;
    }
    __syncthreads();

    // ==================== Layer 1 (input dim 4) ====================
    {   // t1 = M @ x : lane computes cols k0, k0+1
        int k0 = half << 1;
        float t0 = 0.f, t1v = 0.f;
        #pragma unroll
        for (int u = 0; u < 32; ++u) {
            float m = M[n * LDM + u];
            t0  += m * Hb[u * LDH + k0];
            t1v += m * Hb[u * LDH + k0 + 1];
        }
        Ha[n * LDH + k0] = t0;                // Ha free after M-fill barrier
        Ha[n * LDH + k0 + 1] = t1v;
    }
    __syncthreads();

    float h[16];
    {   // h1 = tanh(t1 @ W1 + b1)
        #pragma unroll
        for (int j = 0; j < 16; ++j) {
            int d = d0 + j;
            float acc = sb1[d];
            #pragma unroll
            for (int k = 0; k < 4; ++k) acc += Ha[n * LDH + k] * sW1[k * 32 + d];
            h[j] = tanhf(acc);
        }
    }
    // store h1 (Hb reads of layer1 finished before last barrier)
    {
        float4* hw = reinterpret_cast<float4*>(&Hb[n * LDH + d0]);
        hw[0] = make_float4(h[0], h[1], h[2], h[3]);
        hw[1] = make_float4(h[4], h[5], h[6], h[7]);
        hw[2] = make_float4(h[8], h[9], h[10], h[11]);
        hw[3] = make_float4(h[12], h[13], h[14], h[15]);
    }
    if (n == 0 || n == 16) {
        float* r = &rep[(n == 16) * 96];
        #pragma unroll
        for (int j = 0; j < 16; ++j) r[d0 + j] = h[j];
    }
    __syncthreads();

    // ==================== Layer 2 ====================
    {   // t2 = M @ h1
        float t[16];
        #pragma unroll
        for (int j = 0; j < 16; ++j) t[j] = 0.f;
        #pragma unroll
        for (int u = 0; u < 32; ++u) {
            float m = M[n * LDM + u];
            const float4* hr = reinterpret_cast<const float4*>(&Hb[u * LDH + d0]);
            float4 a = hr[0], bb = hr[1], cc = hr[2], dd = hr[3];
            t[0] += m * a.x;  t[1] += m * a.y;  t[2] += m * a.z;  t[3] += m * a.w;
            t[4] += m * bb.x; t[5] += m * bb.y; t[6] += m * bb.z; t[7] += m * bb.w;
            t[8] += m * cc.x; t[9] += m * cc.y; t[10] += m * cc.z; t[11] += m * cc.w;
            t[12] += m * dd.x; t[13] += m * dd.y; t[14] += m * dd.z; t[15] += m * dd.w;
        }
        float4* tw = reinterpret_cast<float4*>(&Ha[n * LDH + d0]);
        tw[0] = make_float4(t[0], t[1], t[2], t[3]);
        tw[1] = make_float4(t[4], t[5], t[6], t[7]);
        tw[2] = make_float4(t[8], t[9], t[10], t[11]);
        tw[3] = make_float4(t[12], t[13], t[14], t[15]);
    }
    __syncthreads();

    {   // h2 = tanh(t2 @ W2 + b2)
        float tr[32];
        const float4* trp = reinterpret_cast<const float4*>(&Ha[n * LDH]);
        #pragma unroll
        for (int q = 0; q < 8; ++q) {
            float4 v = trp[q];
            tr[4 * q] = v.x; tr[4 * q + 1] = v.y; tr[4 * q + 2] = v.z; tr[4 * q + 3] = v.w;
        }
        float acc[16];
        #pragma unroll
        for (int j = 0; j < 16; ++j) acc[j] = sb2[d0 + j];
        #pragma unroll
        for (int k = 0; k < 32; ++k) {
            float tv = tr[k];
            const float4* wr = reinterpret_cast<const float4*>(&sW2[k * 32 + d0]);
            float4 a = wr[0], bb = wr[1], cc = wr[2], dd = wr[3];
            acc[0] += tv * a.x;  acc[1] += tv * a.y;  acc[2] += tv * a.z;  acc[3] += tv * a.w;
            acc[4] += tv * bb.x; acc[5] += tv * bb.y; acc[6] += tv * bb.z; acc[7] += tv * bb.w;
            acc[8] += tv * cc.x; acc[9] += tv * cc.y; acc[10] += tv * cc.z; acc[11] += tv * cc.w;
            acc[12] += tv * dd.x; acc[13] += tv * dd.y; acc[14] += tv * dd.z; acc[15] += tv * dd.w;
        }
        #pragma unroll
        for (int j = 0; j < 16; ++j) h[j] = tanhf(acc[j]);
    }
    __syncthreads();
    {
        float4* hw = reinterpret_cast<float4*>(&Hb[n * LDH + d0]);
        hw[0] = make_float4(h[0], h[1], h[2], h[3]);
        hw[1] = make_float4(h[4], h[5], h[6], h[7]);
        hw[2] = make_float4(h[8], h[9], h[10], h[11]);
        hw[3] = make_float4(h[12], h[13], h[14], h[15]);
    }
    if (n == 0 || n == 16) {
        float* r = &rep[(n == 16) * 96];
        #pragma unroll
        for (int j = 0; j < 16; ++j) r[32 + d0 + j] = h[j];
    }
    __syncthreads();

    // ==================== Layer 3 (only rows 0 and 16 needed) ====================
    {   // t3[v][k] for v in {0,16}; lane: v = 16*half, k = n
        int v = half << 4;
        float s = 0.f;
        #pragma unroll
        for (int u = 0; u < 32; ++u)
            s += M[v * LDM + u] * Hb[u * LDH + n];
        Ha[half * LDH + n] = s;               // stash in Ha rows 0,1
    }
    __syncthreads();

    {   // h3[v][d] = tanh(t3[v] @ W3 + b3); lane: v-index = half, d = n
        float acc = sb3[n];
        #pragma unroll
        for (int k = 0; k < 32; ++k)
            acc += Ha[half * LDH + k] * sW3[k * 32 + n];
        rep[half * 96 + 64 + n] = tanhf(acc);
    }
    __syncthreads();

    // ==================== Head: relu(cat @ lin1_W + b) @ lin2_W + b ====================
    {
        float acc = 0.f;
        #pragma unroll 8
        for (int k2 = 0; k2 < 96; ++k2) {
            int k = half * 96 + k2;
            acc += rep[k] * lin1W[k * 32 + n];
        }
        acc += __shfl_xor(acc, 32, 64);       // combine the two half-sums
        acc += lin1b[n];
        float hr = fmaxf(acc, 0.f);
        float p = hr * lin2W[n];
        #pragma unroll
        for (int off = 16; off > 0; off >>= 1) p += __shfl_xor(p, off, 64);
        if (l == 0) out[b] = p + lin2b[0];
    }
}

// ---------------------------------------------------------------------------
extern "C" void kernel_launch(void* const* d_in, const int* in_sizes, int n_in,
                              void* d_out, int out_size, void* d_ws, size_t ws_size,
                              hipStream_t stream)
{
    const float* feats = (const float*)d_in[0];
    const int*   row   = (const int*)d_in[1];
    const int*   col   = (const int*)d_in[2];
    const float* W1    = (const float*)d_in[3];
    const float* b1    = (const float*)d_in[4];
    const float* W2    = (const float*)d_in[5];
    const float* b2    = (const float*)d_in[6];
    const float* W3    = (const float*)d_in[7];
    const float* b3    = (const float*)d_in[8];
    const float* lin1W = (const float*)d_in[9];
    const float* lin1b = (const float*)d_in[10];
    const float* lin2W = (const float*)d_in[11];
    const float* lin2b = (const float*)d_in[12];

    const int N = in_sizes[0] / 4;
    const int E = in_sizes[1];
    const int B = N / 32;

    unsigned int* adj = (unsigned int*)d_ws;
    hipMemsetAsync(d_ws, 0, (size_t)B * 1024, stream);

    int eblocks = (E / 4 + 255) / 256;
    if (eblocks > 4096) eblocks = 4096;
    build_adj<<<eblocks, 256, 0, stream>>>(row, col, adj, E);

    igmc_kernel<<<B, 64, 0, stream>>>(
        reinterpret_cast<const float4*>(feats),
        reinterpret_cast<const uchar4*>(adj),
        W1, b1, W2, b2, W3, b3, lin1W, lin1b, lin2W, lin2b,
        (float*)d_out);
}

// Round 2
// 201.644 us; speedup vs baseline: 1.6769x; 1.6769x over previous
//
#include <hip/hip_runtime.h>

typedef __attribute__((ext_vector_type(8))) short bf16x8;
typedef __attribute__((ext_vector_type(16))) float f32x16;

union BF8 { bf16x8 v; unsigned short u[8]; };

static __device__ __forceinline__ unsigned short f2bf(float f) {
    unsigned u = __float_as_uint(f);
    unsigned r = (u + 0x7FFFu + ((u >> 16) & 1u)) >> 16;   // RNE
    return (unsigned short)r;
}

// ---------------------------------------------------------------------------
// Kernel 1: scatter edges into per-block 32x32 u8 count matrices (packed u32)
// ---------------------------------------------------------------------------
__global__ __launch_bounds__(256) void build_adj(
    const int* __restrict__ row, const int* __restrict__ col,
    unsigned int* __restrict__ adj, int E)
{
    const int gid = blockIdx.x * blockDim.x + threadIdx.x;
    const int stride = gridDim.x * blockDim.x;
    const int E4 = E >> 2;
    const int4* row4 = reinterpret_cast<const int4*>(row);
    const int4* col4 = reinterpret_cast<const int4*>(col);
    for (int i = gid; i < E4; i += stride) {
        int4 r = row4[i];
        int4 c = col4[i];
        int idx;
        idx = ((r.x >> 5) << 10) + ((r.x & 31) << 5) + (c.x & 31);
        atomicAdd(&adj[idx >> 2], 1u << ((idx & 3) << 3));
        idx = ((r.y >> 5) << 10) + ((r.y & 31) << 5) + (c.y & 31);
        atomicAdd(&adj[idx >> 2], 1u << ((idx & 3) << 3));
        idx = ((r.z >> 5) << 10) + ((r.z & 31) << 5) + (c.z & 31);
        atomicAdd(&adj[idx >> 2], 1u << ((idx & 3) << 3));
        idx = ((r.w >> 5) << 10) + ((r.w & 31) << 5) + (c.w & 31);
        atomicAdd(&adj[idx >> 2], 1u << ((idx & 3) << 3));
    }
    const int tail = E & 3;
    if (gid < tail) {
        int e = (E4 << 2) + gid;
        int r = row[e], c = col[e];
        int idx = ((r >> 5) << 10) + ((r & 31) << 5) + (c & 31);
        atomicAdd(&adj[idx >> 2], 1u << ((idx & 3) << 3));
    }
}

// ---------------------------------------------------------------------------
// Kernel 2: one wave per subgraph, all matmuls on MFMA (32x32x16 bf16, K=32).
//   A-frag (assumed): row = l&31, k = 16f + 8*(l>>5) + i   (i = 0..7)
//   B-frag (assumed): col = l&31, k = 16f + 8*(l>>5) + i
//   C/D   (verified): col = l&31, row = (q&3) + 8*(q>>2) + 4*(l>>5)
// Any error in the assumed A/B k-mapping cancels: both operands of every
// MFMA are built with the same mapping, and dot-products are k-permutation
// invariant. Only the (verified) C/D mapping must be exact.
// ---------------------------------------------------------------------------
__global__ __launch_bounds__(64, 4) void igmc_kernel(
    const float4* __restrict__ feats4,
    const uchar4* __restrict__ adj4,
    const float* __restrict__ W1, const float* __restrict__ B1,
    const float* __restrict__ W2, const float* __restrict__ B2,
    const float* __restrict__ W3, const float* __restrict__ B3,
    const float* __restrict__ lin1W, const float* __restrict__ lin1b,
    const float* __restrict__ lin2W, const float* __restrict__ lin2b,
    float* __restrict__ out)
{
    __shared__ float Hbuf[32 * 33];   // A-count staging, then layer handoff
    __shared__ float ns[32], nd[32];
    __shared__ float rep[192];        // [user h1|h2|h3 (96) | item h1|h2|h3 (96)]

    const int b = blockIdx.x;
    const int l = threadIdx.x;
    const int h = l >> 5;       // lane half
    const int c = l & 31;       // col (dims) / row (nodes) index, per use

    // ---- stage adjacency counts -> Hbuf[u][v] (LD 33) ----
    #pragma unroll
    for (int j = 0; j < 4; ++j) {
        int q = (l << 2) + j;
        uchar4 cc = adj4[(size_t)b * 256 + q];
        int base = q << 2;
        int u = base >> 5, v = base & 31;
        float* p = &Hbuf[u * 33 + v];
        p[0] = (float)cc.x; p[1] = (float)cc.y; p[2] = (float)cc.z; p[3] = (float)cc.w;
    }
    __syncthreads();

    // ---- degrees -> norms ----
    {
        float s = 0.f;
        if (h == 0) {
            #pragma unroll
            for (int v = 0; v < 32; ++v) s += Hbuf[c * 33 + v];
            ns[c] = rsqrtf(fmaxf(s, 1.f));          // out_deg (row sums)
        } else {
            #pragma unroll
            for (int u = 0; u < 32; ++u) s += Hbuf[u * 33 + c];
            nd[c] = rsqrtf(fmaxf(s, 1.f));          // in_deg (col sums)
        }
    }
    __syncthreads();

    // ---- M A-frags: M[r=c][u] = A[u][c] * ns[u] * nd[c] ----
    const float ndr = nd[c];
    BF8 Mf[2];
    #pragma unroll
    for (int f = 0; f < 2; ++f)
        #pragma unroll
        for (int i = 0; i < 8; ++i) {
            int u = 16 * f + 8 * h + i;
            Mf[f].u[i] = f2bf(Hbuf[u * 33 + c] * ns[u] * ndr);
        }

    // ---- weight B-frags + per-lane scalars (global, coalesced, L2-hot) ----
    const float w1r0 = W1[c], w1r1 = W1[32 + c], w1r2 = W1[64 + c], w1r3 = W1[96 + c];
    const float b1r = B1[c], b2r = B2[c], b3r = B3[c];
    BF8 W2f[2], W3f[2];
    #pragma unroll
    for (int f = 0; f < 2; ++f)
        #pragma unroll
        for (int i = 0; i < 8; ++i) {
            int k = 16 * f + 8 * h + i;
            W2f[f].u[i] = f2bf(W2[k * 32 + c]);
            W3f[f].u[i] = f2bf(W3[k * 32 + c]);
        }

    // ---- H0 = X @ W1 (feats one-hot in general form), as B-frags ----
    BF8 H0f[2];
    #pragma unroll
    for (int f = 0; f < 2; ++f)
        #pragma unroll
        for (int i = 0; i < 8; ++i) {
            int u = 16 * f + 8 * h + i;
            float4 x = feats4[b * 32 + u];
            H0f[f].u[i] = f2bf(x.x * w1r0 + x.y * w1r1 + x.z * w1r2 + x.w * w1r3);
        }
    __syncthreads();   // Hbuf (counts) reads done; buffer free for reuse

    f32x16 acc;
    float hreg[16];
    BF8 Xf[2];

    // ==================== Layer 1: H1 = tanh(M@H0 + b1) ====================
    #pragma unroll
    for (int q = 0; q < 16; ++q) acc[q] = 0.f;
    acc = __builtin_amdgcn_mfma_f32_32x32x16_bf16(Mf[0].v, H0f[0].v, acc, 0, 0, 0);
    acc = __builtin_amdgcn_mfma_f32_32x32x16_bf16(Mf[1].v, H0f[1].v, acc, 0, 0, 0);
    #pragma unroll
    for (int q = 0; q < 16; ++q) hreg[q] = tanhf(acc[q] + b1r);
    if (h == 0) { rep[c] = hreg[0]; rep[96 + c] = hreg[8]; }   // rows 0, 16
    #pragma unroll
    for (int q = 0; q < 16; ++q)
        Hbuf[((q & 3) + 8 * (q >> 2) + 4 * h) * 33 + c] = hreg[q];
    __syncthreads();
    #pragma unroll
    for (int f = 0; f < 2; ++f)
        #pragma unroll
        for (int i = 0; i < 8; ++i) {
            int u = 16 * f + 8 * h + i;
            Xf[f].u[i] = f2bf(Hbuf[u * 33 + c]);   // B-frag of H1
        }
    __syncthreads();

    // ==================== Layer 2 ====================
    #pragma unroll
    for (int q = 0; q < 16; ++q) acc[q] = 0.f;
    acc = __builtin_amdgcn_mfma_f32_32x32x16_bf16(Mf[0].v, Xf[0].v, acc, 0, 0, 0);
    acc = __builtin_amdgcn_mfma_f32_32x32x16_bf16(Mf[1].v, Xf[1].v, acc, 0, 0, 0);
    #pragma unroll
    for (int q = 0; q < 16; ++q)   // T2 -> Hbuf (C layout scatter)
        Hbuf[((q & 3) + 8 * (q >> 2) + 4 * h) * 33 + c] = acc[q];
    __syncthreads();
    #pragma unroll
    for (int f = 0; f < 2; ++f)
        #pragma unroll
        for (int i = 0; i < 8; ++i) {
            int k = 16 * f + 8 * h + i;
            Xf[f].u[i] = f2bf(Hbuf[c * 33 + k]);   // A-frag of T2 (transposed read)
        }
    __syncthreads();
    #pragma unroll
    for (int q = 0; q < 16; ++q) acc[q] = 0.f;
    acc = __builtin_amdgcn_mfma_f32_32x32x16_bf16(Xf[0].v, W2f[0].v, acc, 0, 0, 0);
    acc = __builtin_amdgcn_mfma_f32_32x32x16_bf16(Xf[1].v, W2f[1].v, acc, 0, 0, 0);
    #pragma unroll
    for (int q = 0; q < 16; ++q) hreg[q] = tanhf(acc[q] + b2r);
    if (h == 0) { rep[32 + c] = hreg[0]; rep[96 + 32 + c] = hreg[8]; }
    #pragma unroll
    for (int q = 0; q < 16; ++q)
        Hbuf[((q & 3) + 8 * (q >> 2) + 4 * h) * 33 + c] = hreg[q];
    __syncthreads();
    #pragma unroll
    for (int f = 0; f < 2; ++f)
        #pragma unroll
        for (int i = 0; i < 8; ++i) {
            int u = 16 * f + 8 * h + i;
            Xf[f].u[i] = f2bf(Hbuf[u * 33 + c]);   // B-frag of H2
        }
    __syncthreads();

    // ==================== Layer 3 ====================
    #pragma unroll
    for (int q = 0; q < 16; ++q) acc[q] = 0.f;
    acc = __builtin_amdgcn_mfma_f32_32x32x16_bf16(Mf[0].v, Xf[0].v, acc, 0, 0, 0);
    acc = __builtin_amdgcn_mfma_f32_32x32x16_bf16(Mf[1].v, Xf[1].v, acc, 0, 0, 0);
    #pragma unroll
    for (int q = 0; q < 16; ++q)   // T3 -> Hbuf
        Hbuf[((q & 3) + 8 * (q >> 2) + 4 * h) * 33 + c] = acc[q];
    __syncthreads();
    #pragma unroll
    for (int f = 0; f < 2; ++f)
        #pragma unroll
        for (int i = 0; i < 8; ++i) {
            int k = 16 * f + 8 * h + i;
            Xf[f].u[i] = f2bf(Hbuf[c * 33 + k]);   // A-frag of T3
        }
    #pragma unroll
    for (int q = 0; q < 16; ++q) acc[q] = 0.f;
    acc = __builtin_amdgcn_mfma_f32_32x32x16_bf16(Xf[0].v, W3f[0].v, acc, 0, 0, 0);
    acc = __builtin_amdgcn_mfma_f32_32x32x16_bf16(Xf[1].v, W3f[1].v, acc, 0, 0, 0);
    if (h == 0) {
        rep[64 + c]      = tanhf(acc[0] + b3r);   // row 0
        rep[96 + 64 + c] = tanhf(acc[8] + b3r);   // row 16
    }
    __syncthreads();

    // ==================== Head (fp32 VALU) ====================
    {
        float a = 0.f;
        #pragma unroll 8
        for (int k2 = 0; k2 < 96; ++k2) {
            int k = h * 96 + k2;
            a += rep[k] * lin1W[k * 32 + c];
        }
        a += __shfl_xor(a, 32, 64);               // combine half-sums
        a += lin1b[c];
        float hr = fmaxf(a, 0.f);
        float p = hr * lin2W[c];
        #pragma unroll
        for (int off = 16; off > 0; off >>= 1) p += __shfl_xor(p, off, 64);
        if (l == 0) out[b] = p + lin2b[0];
    }
}

// ---------------------------------------------------------------------------
extern "C" void kernel_launch(void* const* d_in, const int* in_sizes, int n_in,
                              void* d_out, int out_size, void* d_ws, size_t ws_size,
                              hipStream_t stream)
{
    const float* feats = (const float*)d_in[0];
    const int*   row   = (const int*)d_in[1];
    const int*   col   = (const int*)d_in[2];
    const float* W1    = (const float*)d_in[3];
    const float* b1    = (const float*)d_in[4];
    const float* W2    = (const float*)d_in[5];
    const float* b2    = (const float*)d_in[6];
    const float* W3    = (const float*)d_in[7];
    const float* b3    = (const float*)d_in[8];
    const float* lin1W = (const float*)d_in[9];
    const float* lin1b = (const float*)d_in[10];
    const float* lin2W = (const float*)d_in[11];
    const float* lin2b = (const float*)d_in[12];

    const int N = in_sizes[0] / 4;
    const int E = in_sizes[1];
    const int B = N / 32;

    unsigned int* adj = (unsigned int*)d_ws;
    hipMemsetAsync(d_ws, 0, (size_t)B * 1024, stream);

    int eblocks = (E / 4 + 255) / 256;
    if (eblocks > 4096) eblocks = 4096;
    build_adj<<<eblocks, 256, 0, stream>>>(row, col, adj, E);

    igmc_kernel<<<B, 64, 0, stream>>>(
        reinterpret_cast<const float4*>(feats),
        reinterpret_cast<const uchar4*>(adj),
        W1, b1, W2, b2, W3, b3, lin1W, lin1b, lin2W, lin2b,
        (float*)d_out);
}